// Round 3
// baseline (214.916 us; speedup 1.0000x reference)
//
#include <hip/hip_runtime.h>
#include <stdint.h>

typedef unsigned long long u64;

#define N 8192
#define NW 128            // 64-bit words per mask row
#define NBLK 128          // N/64
#define MAX_OUT 256
#define MASK_BYTES ((size_t)N * NW * 8)   // 8 MiB

// ws layout:
//   [0, 8MB)    mask u64[N][NW]
//     overlap (dead before mask_kernel writes):
//       ws+0    rank_part int[8][N]  (256 KB)
//   +8MB        order  int[N]     32 KB
//   +32KB       s_s    float[N]   32 KB
//   +64KB       bbox   float4[N] 128 KB
//   +192KB      area   float[N]   32 KB

__device__ __forceinline__ u64 score_key(float s, int idx) {
    // non-negative floats: uint bit pattern order-preserving.
    // ~bits<<32 | idx → ascending == score desc, idx asc (stable argsort).
    uint32_t b = __float_as_uint(s);
    return ((u64)(~b) << 32) | (uint32_t)idx;
}

// ---------------- Kernel 1: partial ranks (keys built on the fly) ----------------
// rank_part[jc][i] = #{j in chunk jc : key[j] < key[i]}. No atomics, no init.
__global__ __launch_bounds__(256)
void rank_kernel(const float* __restrict__ score, int* __restrict__ rank_part) {
    __shared__ u64 kj[1024];
    const int tid = threadIdx.x;
    const int jbase = blockIdx.y * 1024;
    for (int t = tid; t < 1024; t += 256)
        kj[t] = score_key(score[jbase + t], jbase + t);
    __syncthreads();
    const int i = blockIdx.x * 256 + tid;
    const u64 ki = score_key(score[i], i);
    int c = 0;
    #pragma unroll 8
    for (int j = 0; j < 1024; ++j) c += (kj[j] < ki) ? 1 : 0;
    rank_part[blockIdx.y * N + i] = c;
}

// ---------------- Kernel 2: scatter to sorted order + precompute ----------------
__global__ __launch_bounds__(256)
void scatter_kernel(const float* __restrict__ score, const float* __restrict__ box,
                    const int* __restrict__ rank_part, int* __restrict__ order,
                    float* __restrict__ s_s, float4* __restrict__ bbox,
                    float* __restrict__ area) {
    int i = blockIdx.x * 256 + threadIdx.x;
    int r = 0;
    #pragma unroll
    for (int p = 0; p < 8; ++p) r += rank_part[p * N + i];
    float s = score[i];
    order[r] = i;
    s_s[r] = s;
    float cx = box[i*16 + 0], cy = box[i*16 + 1];
    float w  = box[i*16 + 2], h  = box[i*16 + 3];
    float hw = w * 0.5f, hh = h * 0.5f;
    float x0 = cx - hw, y0 = cy - hh, x1 = cx + hw, y1 = cy + hh;
    bbox[r] = make_float4(x0, y0, x1, y1);
    area[r] = (x1 - x0) * (y1 - y0);   // replicate ref: area from xyxy
}

// ---------------- Kernel 3: suppression bitmask (upper triangle, valid rows) ----------------
__global__ __launch_bounds__(256)
void mask_kernel(const float4* __restrict__ bbox, const float* __restrict__ area,
                 const float* __restrict__ s_s, u64* __restrict__ mask) {
    const int w = blockIdx.x;
    const int i = blockIdx.y * 256 + threadIdx.x;
    __shared__ float4 jb[64];
    __shared__ float  ja[64];
    if (threadIdx.x < 64) {
        jb[threadIdx.x] = bbox[w * 64 + threadIdx.x];
        ja[threadIdx.x] = area[w * 64 + threadIdx.x];
    }
    __syncthreads();
    if (w < (i >> 6)) return;          // lower triangle: never read
    if (s_s[i] < 0.3f) return;         // invalid rows: never read
    float4 a = bbox[i];
    float  aa = area[i];
    u64 bits = 0;
    #pragma unroll 8
    for (int jj = 0; jj < 64; ++jj) {
        float4 b = jb[jj];
        float lx = fmaxf(a.x, b.x), ly = fmaxf(a.y, b.y);
        float rx = fminf(a.z, b.z), ry = fminf(a.w, b.w);
        float ww = fmaxf(rx - lx, 0.0f), hh = fmaxf(ry - ly, 0.0f);
        float inter = ww * hh;
        float denom = ((aa + ja[jj]) - inter) + 1e-9f;  // exact ref op order
        float iou = inter / denom;                       // IEEE div, matches np
        bits |= ((u64)(iou > 0.3f)) << jj;
    }
    mask[(size_t)i * NW + w] = bits;
}

// ---------------- Kernel 4: serial greedy pass (single wave), pipelined ----------------
// remv words distributed 2/lane. Keeps of block b:
//   - word b+1 of each kept row: wave-uniform BROADCAST loads (no reduce),
//     issued post-while(b), consumed at A(b+1) — the one irreducible RT.
//   - full row (2 words/lane): issued post-while(b), consumed post-while(b+1)
//     (a whole block in flight → off the critical path), feeding remv for b+2+.
// Col word + scores for block b+1 prefetched at A(b). All slot arrays are
// fully unrolled with zeroed unused slots so they stay in VGPRs.
__global__ __launch_bounds__(64)
void nms_kernel(const u64* __restrict__ mask, const float* __restrict__ s_s,
                const int* __restrict__ order, const float* __restrict__ box,
                float* __restrict__ out) {
    const int lane = threadIdx.x;
    __shared__ int kpos[MAX_OUT];
    u64 remv0 = 0, remv1 = 0;        // lane l owns words 2l, 2l+1
    int kcount = 0;
    u64 pA0[8], pA1[8], lateW[8];
    #pragma unroll
    for (int j = 0; j < 8; ++j) { pA0[j] = 0; pA1[j] = 0; lateW[j] = 0; }
    u64 lateOvf = 0;

    u64 col_cur = mask[(size_t)lane * NW + 0];
    float sc_cur = s_s[lane];

    for (int b = 0; b < NBLK; ++b) {
        const int base = b << 6;
        // ---- Phase A: prefetch next block, assemble supp word ----
        u64 col_next = 0; float sc_next = 0.0f;
        if (b + 1 < NBLK) {
            col_next = mask[(size_t)(base + 64 + lane) * NW + (b + 1)];
            sc_next = s_s[base + 64 + lane];
        }
        u64 validm = __ballot(sc_cur >= 0.3f);
        if (validm == 0) break;      // scores sorted: all later blocks invalid too
        u64 supp_late = lateOvf;
        lateOvf = 0;
        #pragma unroll
        for (int j = 0; j < 8; ++j) supp_late |= lateW[j];
        u64 sel = (b & 1) ? remv1 : remv0;
        int owner = b >> 1;
        unsigned lo = __shfl((int)(unsigned)sel, owner);
        unsigned hi = __shfl((int)(unsigned)(sel >> 32), owner);
        u64 supp = (((u64)hi << 32) | lo) | supp_late;
        // ---- Phase B: in-block resolve (ballot row reconstruction, symmetry) ----
        u64 todo = validm & ~supp;
        u64 col = col_cur;
        u64 km = 0;
        while (todo) {
            int l = (int)__builtin_ctzll(todo);
            u64 row_l = __ballot(((col >> l) & 1ull) != 0);
            if (lane == 0) kpos[kcount] = base + l;
            km |= (1ull << l);
            kcount++;
            todo &= ~row_l;
            todo &= ~(1ull << l);
            if (kcount >= MAX_OUT) break;
        }
        if (kcount >= MAX_OUT) break;
        // ---- Phase C: retire previous pending, issue this block's loads ----
        #pragma unroll
        for (int j = 0; j < 8; ++j) { remv0 |= pA0[j]; remv1 |= pA1[j]; }
        int rows[8];
        u64 t = km;
        #pragma unroll
        for (int j = 0; j < 8; ++j) {
            if (t) { rows[j] = base + (int)__builtin_ctzll(t); t &= t - 1; }
            else rows[j] = -1;
        }
        const int wl = (b + 1 < NBLK) ? (b + 1) : 0;   // guarded; unused if b+1==NBLK
        #pragma unroll
        for (int j = 0; j < 8; ++j) {
            if (rows[j] >= 0) {
                const u64* rp = mask + (size_t)rows[j] * NW;
                pA0[j] = rp[2 * lane];
                pA1[j] = rp[2 * lane + 1];
                lateW[j] = rp[wl];           // broadcast load (uniform addr)
            } else { pA0[j] = 0; pA1[j] = 0; lateW[j] = 0; }
        }
        // overflow (>8 keeps in one block, rare): synchronous
        while (t) {
            int l = (int)__builtin_ctzll(t); t &= t - 1;
            const u64* rp = mask + (size_t)(base + l) * NW;
            remv0 |= rp[2 * lane];
            remv1 |= rp[2 * lane + 1];
            lateOvf |= rp[wl];
        }
        col_cur = col_next; sc_cur = sc_next;
    }
    __syncthreads();
    // outputs: [score 256][box 256*16][valid 256], all float32
    float* out_score = out;
    float* out_box   = out + MAX_OUT;
    float* out_valid = out + MAX_OUT + MAX_OUT * 16;
    const float4* box4 = (const float4*)box;
    float4* ob4 = (float4*)out_box;
    for (int t2 = lane; t2 < MAX_OUT; t2 += 64) {
        if (t2 < kcount) {
            int p = kpos[t2];
            out_score[t2] = s_s[p];
            out_valid[t2] = 1.0f;
            int oi = order[p];
            #pragma unroll
            for (int q = 0; q < 4; ++q) ob4[t2 * 4 + q] = box4[oi * 4 + q];
        } else {
            out_score[t2] = 0.0f;
            out_valid[t2] = 0.0f;
            float4 z = make_float4(0.f, 0.f, 0.f, 0.f);
            #pragma unroll
            for (int q = 0; q < 4; ++q) ob4[t2 * 4 + q] = z;
        }
    }
}

extern "C" void kernel_launch(void* const* d_in, const int* in_sizes, int n_in,
                              void* d_out, int out_size, void* d_ws, size_t ws_size,
                              hipStream_t stream) {
    const float* score = (const float*)d_in[0];   // (8192,1) f32
    const float* box   = (const float*)d_in[1];   // (8192,16) f32
    char* ws = (char*)d_ws;
    u64*    mask      = (u64*)ws;
    int*    rank_part = (int*)ws;                 // overlap, dead before mask
    int*    order  = (int*)   (ws + MASK_BYTES);
    float*  s_s    = (float*) (ws + MASK_BYTES + 32768);
    float4* bbox   = (float4*)(ws + MASK_BYTES + 65536);
    float*  area   = (float*) (ws + MASK_BYTES + 65536 + 131072);

    rank_kernel<<<dim3(32, 8), 256, 0, stream>>>(score, rank_part);
    scatter_kernel<<<32, 256, 0, stream>>>(score, box, rank_part, order, s_s, bbox, area);
    mask_kernel<<<dim3(128, 32), 256, 0, stream>>>(bbox, area, s_s, mask);
    nms_kernel<<<1, 64, 0, stream>>>(mask, s_s, order, box, (float*)d_out);
}